// Round 1
// baseline (94.542 us; speedup 1.0000x reference)
//
#include <hip/hip_runtime.h>

// Problem constants (fixed by setup_inputs): B=32, NP=8732, NT=128.
#define NPRED 8732
#define NTRUE 128
#define NBATCH 32
#define BLOCK 256
#define CHUNKS ((NPRED + BLOCK - 1) / BLOCK)   // 35
#define NBLK (NBATCH * CHUNKS)                 // 1120

__global__ __launch_bounds__(BLOCK) void mbloss_pair_kernel(
    const float* __restrict__ pb, const float* __restrict__ pp,
    const float* __restrict__ tb, const float* __restrict__ tp,
    float* __restrict__ partials)
{
    __shared__ float4 s_raw[NTRUE];   // tx1, ty1, tx2, ty2 (raw coords)
    __shared__ float4 s_d1[NTRUE];    // tcx(*150), tcy(*150), twx*300, twy*300
    __shared__ float2 s_d2[NTRUE];    // area_t, tp
    __shared__ float  s_red[BLOCK / 64];

    const int b     = blockIdx.x / CHUNKS;
    const int chunk = blockIdx.x % CHUNKS;
    const int tid   = threadIdx.x;
    const int p     = chunk * BLOCK + tid;

    if (tid < NTRUE) {
        float4 t   = ((const float4*)tb)[b * NTRUE + tid];
        float  tpv = tp[b * NTRUE + tid];
        float  twx = fabsf(t.x - t.z);
        float  twy = fabsf(t.y - t.w);
        s_raw[tid] = t;
        s_d1[tid]  = make_float4((t.x + t.z) * 150.f, (t.y + t.w) * 150.f,
                                 twx * 300.f, twy * 300.f);
        s_d2[tid]  = make_float2(twx * twy, tpv);
    }
    __syncthreads();

    float acc = 0.f;
    if (p < NPRED) {
        float4 pbox = ((const float4*)pb)[b * NPRED + p];
        float  ppv  = pp[b * NPRED + p];
        const float px1 = pbox.x, py1 = pbox.y, px2 = pbox.z, py2 = pbox.w;
        const float pwx = fabsf(px1 - px2), pwy = fabsf(py1 - py2);
        const float area_p = pwx * pwy;
        const float pcx = (px1 + px2) * 150.f, pcy = (py1 + py2) * 150.f;
        const float pwx3 = pwx * 300.f, pwy3 = pwy * 300.f;

        #pragma unroll 4
        for (int t = 0; t < NTRUE; ++t) {
            float4 tr = s_raw[t];
            float4 td = s_d1[t];
            float2 te = s_d2[t];
            // IoU pieces (no division: iou<0.5 <=> inter < 0.5*denom)
            float xd    = fminf(px2, tr.z) - fmaxf(px1, tr.x);
            float yd    = fminf(py2, tr.w) - fmaxf(py1, tr.y);
            float inter = (xd > 0.f && yd > 0.f) ? xd * yd : 0.f;
            float denom = area_p + te.x - inter;
            // classification branch: |pp - tp| ** 0.1 == exp2(0.1*log2(|d|))
            float dcls = fabsf(ppv - te.y);
            float cls  = __builtin_amdgcn_exp2f(0.1f * __builtin_amdgcn_logf(dcls));
            // box branch
            float dx  = pcx  - td.x;
            float dy  = pcy  - td.y;
            float dwx = pwx3 - td.z;
            float dwy = pwy3 - td.w;
            float box = dx * dx;
            box = fmaf(dy,  dy,  box);
            box = fmaf(dwx, dwx, box);
            box = fmaf(dwy, dwy, box);
            acc += (inter < 0.5f * denom) ? cls : box;
        }
    }

    // wave (64-lane) reduction, then cross-wave via LDS
    #pragma unroll
    for (int off = 32; off > 0; off >>= 1)
        acc += __shfl_down(acc, off, 64);
    if ((tid & 63) == 0) s_red[tid >> 6] = acc;
    __syncthreads();
    if (tid == 0) {
        float s = 0.f;
        #pragma unroll
        for (int w = 0; w < BLOCK / 64; ++w) s += s_red[w];
        partials[blockIdx.x] = s;
    }
}

__global__ __launch_bounds__(256) void mbloss_reduce_kernel(
    const float* __restrict__ partials, float* __restrict__ out)
{
    __shared__ double s_red[4];
    const int tid = threadIdx.x;
    double acc = 0.0;
    for (int i = tid; i < NBLK; i += 256) acc += (double)partials[i];
    #pragma unroll
    for (int off = 32; off > 0; off >>= 1)
        acc += __shfl_down(acc, off, 64);
    if ((tid & 63) == 0) s_red[tid >> 6] = acc;
    __syncthreads();
    if (tid == 0) {
        double s = 0.0;
        #pragma unroll
        for (int w = 0; w < 4; ++w) s += s_red[w];
        out[0] = (float)s;
    }
}

extern "C" void kernel_launch(void* const* d_in, const int* in_sizes, int n_in,
                              void* d_out, int out_size, void* d_ws, size_t ws_size,
                              hipStream_t stream) {
    const float* pb = (const float*)d_in[0];  // [B, NP, 4]
    const float* pp = (const float*)d_in[1];  // [B, NP]
    const float* tb = (const float*)d_in[2];  // [B, NT, 4]
    const float* tp = (const float*)d_in[3];  // [B, NT]
    float* partials = (float*)d_ws;           // NBLK floats

    mbloss_pair_kernel<<<NBLK, BLOCK, 0, stream>>>(pb, pp, tb, tp, partials);
    mbloss_reduce_kernel<<<1, 256, 0, stream>>>(partials, (float*)d_out);
}

// Round 2
// 90.427 us; speedup vs baseline: 1.0455x; 1.0455x over previous
//
#include <hip/hip_runtime.h>

// Problem constants (fixed by setup_inputs): B=32, NP=8732, NT=128.
#define NPRED 8732
#define NTRUE 128
#define NBATCH 32
#define BLOCK 128
#define CHUNKS ((NPRED + BLOCK - 1) / BLOCK)   // 69
#define NBLK (NBATCH * CHUNKS)                 // 2208

__global__ __launch_bounds__(BLOCK) void mbloss_pair_kernel(
    const float* __restrict__ pb, const float* __restrict__ pp,
    const float* __restrict__ tb, const float* __restrict__ tp,
    float* __restrict__ partials)
{
    __shared__ float4 s_t1[NTRUE];   // tx1, ty1, tx2, ty2 (raw coords)
    __shared__ float4 s_t2[NTRUE];   // -2*tcx, -2*tcy, -2*twx3, -2*twy3
    __shared__ float4 s_t3[NTRUE];   // area_t, tp, B2, pad
    __shared__ float  s_red[BLOCK / 64];

    const int b     = blockIdx.x / CHUNKS;
    const int chunk = blockIdx.x % CHUNKS;
    const int tid   = threadIdx.x;
    const int p     = chunk * BLOCK + tid;

    {
        float4 t   = ((const float4*)tb)[b * NTRUE + tid];
        float  tpv = tp[b * NTRUE + tid];
        float  tcx = (t.x + t.z) * 150.f;
        float  tcy = (t.y + t.w) * 150.f;
        float  twx = fabsf(t.x - t.z);
        float  twy = fabsf(t.y - t.w);
        float  tw3 = twx * 300.f;
        float  th3 = twy * 300.f;
        float  b2  = tcx * tcx + tcy * tcy + tw3 * tw3 + th3 * th3;
        s_t1[tid] = t;
        s_t2[tid] = make_float4(-2.f * tcx, -2.f * tcy, -2.f * tw3, -2.f * th3);
        s_t3[tid] = make_float4(twx * twy, tpv, b2, 0.f);
    }
    __syncthreads();

    float acc = 0.f;
    if (p < NPRED) {
        float4 pbox = ((const float4*)pb)[b * NPRED + p];
        float  ppv  = pp[b * NPRED + p];
        const float px1 = pbox.x, py1 = pbox.y, px2 = pbox.z, py2 = pbox.w;
        const float pwx = fabsf(px1 - px2), pwy = fabsf(py1 - py2);
        const float area_p = pwx * pwy;
        const float pcx = (px1 + px2) * 150.f, pcy = (py1 + py2) * 150.f;
        const float pwx3 = pwx * 300.f, pwy3 = pwy * 300.f;
        const float a2 = pcx * pcx + pcy * pcy + pwx3 * pwx3 + pwy3 * pwy3;

        #pragma unroll 8
        for (int t = 0; t < NTRUE; ++t) {
            float4 r = s_t1[t];
            float4 m = s_t2[t];
            float4 e = s_t3[t];
            // intersection: max(xd,0)*max(yd,0) == where(xd>0 & yd>0, xd*yd, 0)
            float xd    = fminf(px2, r.z) - fmaxf(px1, r.x);
            float yd    = fminf(py2, r.w) - fmaxf(py1, r.y);
            float inter = fmaxf(xd, 0.f) * fmaxf(yd, 0.f);
            // iou<0.5  <=>  inter < 0.5*(Ap+At-inter)  <=>  3*inter < Ap+At
            float sarea = area_p + e.x;
            // classification: |pp-tp|^0.1 = exp2(0.1*log2(|d|)); abs folds to src mod
            float dcls = ppv - e.y;
            float cls  = __builtin_amdgcn_exp2f(0.1f * __builtin_amdgcn_logf(fabsf(dcls)));
            // box: sum (p_i-t_i)^2 = A2 + B2 + sum p_i*(-2 t_i)
            float box = fmaf(pcx,  m.x, a2 + e.z);
            box = fmaf(pcy,  m.y, box);
            box = fmaf(pwx3, m.z, box);
            box = fmaf(pwy3, m.w, box);
            acc += (3.f * inter < sarea) ? cls : box;
        }
    }

    // wave (64-lane) reduction, then cross-wave via LDS
    #pragma unroll
    for (int off = 32; off > 0; off >>= 1)
        acc += __shfl_down(acc, off, 64);
    if ((tid & 63) == 0) s_red[tid >> 6] = acc;
    __syncthreads();
    if (tid == 0) {
        float s = 0.f;
        #pragma unroll
        for (int w = 0; w < BLOCK / 64; ++w) s += s_red[w];
        partials[blockIdx.x] = s;
    }
}

__global__ __launch_bounds__(256) void mbloss_reduce_kernel(
    const float* __restrict__ partials, float* __restrict__ out)
{
    __shared__ double s_red[4];
    const int tid = threadIdx.x;
    double acc = 0.0;
    for (int i = tid; i < NBLK; i += 256) acc += (double)partials[i];
    #pragma unroll
    for (int off = 32; off > 0; off >>= 1)
        acc += __shfl_down(acc, off, 64);
    if ((tid & 63) == 0) s_red[tid >> 6] = acc;
    __syncthreads();
    if (tid == 0) {
        double s = 0.0;
        #pragma unroll
        for (int w = 0; w < 4; ++w) s += s_red[w];
        out[0] = (float)s;
    }
}

extern "C" void kernel_launch(void* const* d_in, const int* in_sizes, int n_in,
                              void* d_out, int out_size, void* d_ws, size_t ws_size,
                              hipStream_t stream) {
    const float* pb = (const float*)d_in[0];  // [B, NP, 4]
    const float* pp = (const float*)d_in[1];  // [B, NP]
    const float* tb = (const float*)d_in[2];  // [B, NT, 4]
    const float* tp = (const float*)d_in[3];  // [B, NT]
    float* partials = (float*)d_ws;           // NBLK floats

    mbloss_pair_kernel<<<NBLK, BLOCK, 0, stream>>>(pb, pp, tb, tp, partials);
    mbloss_reduce_kernel<<<1, 256, 0, stream>>>(partials, (float*)d_out);
}